// Round 1
// baseline (5310.281 us; speedup 1.0000x reference)
//
#include <hip/hip_runtime.h>

// DIMKT round 0: correctness-first multi-kernel graph implementation.
// Structure:
//   - precompute: transpose+bf16 weight slices (14), embedding@weight tables (9 GEMMs)
//   - scan: 199 steps x { k1: sdf = act(d@Ws1,d@Ws2), gamma = act(h@Wki_h + KIb);
//                         k2: pka = act(sdf@Wp1a,sdf@Wp2a), h' = g*h+(1-g)*pka,
//                             d' = x_{t+1}-h', dot-partials for y }
//   - finalize: y = sigmoid(sum dotparts), last col 0.

typedef unsigned short u16;
using f32x4 = __attribute__((ext_vector_type(4))) float;
using bf16x8 = __attribute__((ext_vector_type(8))) short;

#define DEV static __device__ __forceinline__

#define Bv 512
#define Sv 200
#define Dv 512

DEV u16 f2bf(float f) {
  unsigned int u = __float_as_uint(f);
  unsigned int r = (u + 0x7fffu + ((u >> 16) & 1u)) >> 16;
  return (u16)r;
}
DEV float bf2f(u16 h) { return __uint_as_float(((unsigned int)h) << 16); }
DEV float sigm(float x) { return 1.0f / (1.0f + __expf(-x)); }
DEV float tanh_(float x) {
  x = fmaxf(fminf(x, 15.f), -15.f);
  float e = __expf(2.0f * x);
  return (e - 1.0f) / (e + 1.0f);
}

// ---------------- tiled bf16 MFMA GEMM core: C[64x64] += A[64x512] @ B[512x64] ----------------
// A: row-major [M x 512] (f32 or bf16). B: pre-transposed bf16 [N x 512] (row n = col of W).
// LDS tiles stride 40 elems (80B): 16B-aligned rows, 2-way-max bank aliasing (free).
// MFMA 16x16x32 layouts (m89-verified): A/B frag: idx=lane&15 (row of A / col of B),
// k = (lane>>4)*8 + j (contiguous -> ds_read_b128). C: col=lane&15, row=(lane>>4)*4+reg.
template <int NB, bool AF32>
DEV void gemm_tiles(const void* __restrict__ Aptr, int mvalid,
                    const u16* __restrict__ BT0, const u16* __restrict__ BT1,
                    u16* ldsA, u16* ldsB0, u16* ldsB1, int tid,
                    f32x4* acc0, f32x4* acc1) {
  const int lane = tid & 63, wid = tid >> 6;
  const int fr = lane & 15, fq = lane >> 4;
  const int srow = tid >> 2, sseg = tid & 3;  // staging: 4 threads/row, 8 elems each

  for (int kt = 0; kt < 16; ++kt) {
    const int k0 = kt * 32;
    // stage A tile [64 rows x 32 k]
    {
      bf16x8 pack;
      if constexpr (AF32) {
        if (srow < mvalid) {
          const float4* ap = (const float4*)((const float*)Aptr + (size_t)srow * 512 + k0 + sseg * 8);
          float4 v0 = ap[0], v1 = ap[1];
          pack[0] = (short)f2bf(v0.x); pack[1] = (short)f2bf(v0.y);
          pack[2] = (short)f2bf(v0.z); pack[3] = (short)f2bf(v0.w);
          pack[4] = (short)f2bf(v1.x); pack[5] = (short)f2bf(v1.y);
          pack[6] = (short)f2bf(v1.z); pack[7] = (short)f2bf(v1.w);
        } else {
          for (int j = 0; j < 8; ++j) pack[j] = 0;
        }
      } else {
        pack = *(const bf16x8*)((const u16*)Aptr + (size_t)srow * 512 + k0 + sseg * 8);
      }
      *(bf16x8*)&ldsA[srow * 40 + sseg * 8] = pack;
      *(bf16x8*)&ldsB0[srow * 40 + sseg * 8] =
          *(const bf16x8*)(BT0 + (size_t)srow * 512 + k0 + sseg * 8);
      if constexpr (NB == 2)
        *(bf16x8*)&ldsB1[srow * 40 + sseg * 8] =
            *(const bf16x8*)(BT1 + (size_t)srow * 512 + k0 + sseg * 8);
    }
    __syncthreads();
    bf16x8 a = *(const bf16x8*)&ldsA[(wid * 16 + fr) * 40 + fq * 8];
#pragma unroll
    for (int ni = 0; ni < 4; ++ni) {
      bf16x8 b0 = *(const bf16x8*)&ldsB0[(ni * 16 + fr) * 40 + fq * 8];
      acc0[ni] = __builtin_amdgcn_mfma_f32_16x16x32_bf16(a, b0, acc0[ni], 0, 0, 0);
      if constexpr (NB == 2) {
        bf16x8 b1 = *(const bf16x8*)&ldsB1[(ni * 16 + fr) * 40 + fq * 8];
        acc1[ni] = __builtin_amdgcn_mfma_f32_16x16x32_bf16(a, b1, acc1[ni], 0, 0, 0);
      }
    }
    __syncthreads();
  }
}

// ---------------- precompute: table GEMM C[Mx512] = A[Mx512] @ W, optional +bias ----------------
template <bool F32OUT>
__global__ __launch_bounds__(256) void gemm_table_k(const float* __restrict__ A, int M,
                                                    const u16* __restrict__ BT,
                                                    const float* __restrict__ bias,
                                                    void* __restrict__ C) {
  __shared__ u16 ldsA[64 * 40], ldsB[64 * 40];
  const int m0 = blockIdx.x * 64, n0 = blockIdx.y * 64;
  const int tid = threadIdx.x;
  f32x4 acc[4] = {};
  gemm_tiles<1, true>(A + (size_t)m0 * 512, M - m0, BT + (size_t)n0 * 512, nullptr,
                      ldsA, ldsB, nullptr, tid, acc, nullptr);
  const int lane = tid & 63, wid = tid >> 6, fr = lane & 15, fq = lane >> 4;
#pragma unroll
  for (int ni = 0; ni < 4; ++ni) {
    int col = n0 + ni * 16 + fr;
    float bv = bias ? bias[col] : 0.f;
#pragma unroll
    for (int r = 0; r < 4; ++r) {
      int row = m0 + wid * 16 + fq * 4 + r;
      if (row < M) {
        float v = acc[ni][r] + bv;
        if constexpr (F32OUT)
          ((float*)C)[(size_t)row * 512 + col] = v;
        else
          ((u16*)C)[(size_t)row * 512 + col] = f2bf(v);
      }
    }
  }
}

// ---------------- weight transpose+convert: src f32 [512][512] -> dst bf16 [n][k] ----------------
__global__ __launch_bounds__(256) void convT_k(const float* __restrict__ src, u16* __restrict__ dst) {
  __shared__ float tile[32][33];
  const int bi = blockIdx.x, bj = blockIdx.y;  // bi: n block, bj: k block
  const int tx = threadIdx.x & 31, ty = threadIdx.x >> 5;  // ty 0..7
#pragma unroll
  for (int r = 0; r < 4; ++r)
    tile[ty + 8 * r][tx] = src[(size_t)(bj * 32 + ty + 8 * r) * 512 + bi * 32 + tx];
  __syncthreads();
#pragma unroll
  for (int r = 0; r < 4; ++r)
    dst[(size_t)(bi * 32 + ty + 8 * r) * 512 + bj * 32 + tx] = f2bf(tile[tx][ty + 8 * r]);
}

// ---------------- prologue: h=h0, d = x_0 - h0 ----------------
__global__ __launch_bounds__(256) void prologue_k(
    const float* __restrict__ h0, const int* __restrict__ q_seq, const int* __restrict__ c_seq,
    const int* __restrict__ qd_seq, const int* __restrict__ cd_seq,
    const float* __restrict__ XQ, const float* __restrict__ XC, const float* __restrict__ XQD,
    const float* __restrict__ XCD, float* __restrict__ h_f32, u16* __restrict__ h_bf,
    u16* __restrict__ d_buf) {
  const int i = blockIdx.x * 256 + threadIdx.x;  // 0 .. 512*512-1
  const int b = i >> 9, col = i & 511;
  float h = h0[i];
  int qi = q_seq[b * Sv], cci = c_seq[b * Sv], qdi = qd_seq[b * Sv], cdi = cd_seq[b * Sv];
  float x = XQ[(size_t)qi * 512 + col] + XC[(size_t)cci * 512 + col] +
            XQD[(size_t)qdi * 512 + col] + XCD[(size_t)cdi * 512 + col];
  h_f32[i] = h;
  h_bf[i] = f2bf(h);
  d_buf[i] = f2bf(x - h);
}

// ---------------- scan phase 1: sdf (blocks 0..63) and gamma (blocks 64..127) ----------------
__global__ __launch_bounds__(256) void k1_kernel(
    const u16* __restrict__ d_buf, const u16* __restrict__ h_bf,
    const u16* __restrict__ Ws1T, const u16* __restrict__ Ws2T, const u16* __restrict__ WkihT,
    const float* __restrict__ b_s1, const float* __restrict__ b_s2,
    const u16* __restrict__ Kcorr, const u16* __restrict__ Kqd, const u16* __restrict__ Kcd,
    const int* __restrict__ corr_seq, const int* __restrict__ qd_seq, const int* __restrict__ cd_seq,
    u16* __restrict__ sdf, float* __restrict__ gamma, int t) {
  __shared__ u16 ldsA[64 * 40], ldsB0[64 * 40], ldsB1[64 * 40];
  const int bid = blockIdx.x, tid = threadIdx.x;
  const int lane = tid & 63, wid = tid >> 6, fr = lane & 15, fq = lane >> 4;
  if (bid < 64) {
    const int m0 = (bid >> 3) * 64, n0 = (bid & 7) * 64;
    f32x4 acc0[4] = {}, acc1[4] = {};
    gemm_tiles<2, false>(d_buf + (size_t)m0 * 512, 64, Ws1T + (size_t)n0 * 512,
                         Ws2T + (size_t)n0 * 512, ldsA, ldsB0, ldsB1, tid, acc0, acc1);
#pragma unroll
    for (int ni = 0; ni < 4; ++ni) {
      int col = n0 + ni * 16 + fr;
      float bs1 = b_s1[col], bs2 = b_s2[col];
#pragma unroll
      for (int r = 0; r < 4; ++r) {
        int row = m0 + wid * 16 + fq * 4 + r;
        float u1 = acc0[ni][r] + bs1;
        float u2 = acc1[ni][r] + bs2;
        sdf[(size_t)row * 512 + col] = f2bf(sigm(u1) * tanh_(u2));
      }
    }
  } else {
    const int id = bid - 64;
    const int m0 = (id >> 3) * 64, n0 = (id & 7) * 64;
    f32x4 acc0[4] = {};
    gemm_tiles<1, false>(h_bf + (size_t)m0 * 512, 64, WkihT + (size_t)n0 * 512, nullptr,
                         ldsA, ldsB0, nullptr, tid, acc0, nullptr);
#pragma unroll
    for (int r = 0; r < 4; ++r) {
      int row = m0 + wid * 16 + fq * 4 + r;
      int ci = corr_seq[row * Sv + t];
      int qdi = qd_seq[row * Sv + t];
      int cdi = cd_seq[row * Sv + t];
#pragma unroll
      for (int ni = 0; ni < 4; ++ni) {
        int col = n0 + ni * 16 + fr;
        float kib = bf2f(Kcorr[ci * 512 + col]) + bf2f(Kqd[qdi * 512 + col]) +
                    bf2f(Kcd[cdi * 512 + col]);
        gamma[(size_t)row * 512 + col] = sigm(acc0[ni][r] + kib);
      }
    }
  }
}

// ---------------- scan phase 2: pka, h update, d update, y dot-partials ----------------
__global__ __launch_bounds__(256) void k2_kernel(
    const u16* __restrict__ sdf, const u16* __restrict__ Wp1aT, const u16* __restrict__ Wp2aT,
    const u16* __restrict__ P1c, const u16* __restrict__ P2c,
    const int* __restrict__ corr_seq, const int* __restrict__ q_seq, const int* __restrict__ c_seq,
    const int* __restrict__ qd_seq, const int* __restrict__ cd_seq,
    const float* __restrict__ XQ, const float* __restrict__ XC, const float* __restrict__ XQD,
    const float* __restrict__ XCD, const float* __restrict__ gamma,
    float* __restrict__ h_f32, u16* __restrict__ h_bf, u16* __restrict__ d_buf,
    float* __restrict__ dotpart, int t) {
  __shared__ u16 ldsA[64 * 40], ldsB0[64 * 40], ldsB1[64 * 40];
  const int bid = blockIdx.x, tid = threadIdx.x;
  const int m0 = (bid >> 3) * 64, nb = bid & 7, n0 = nb * 64;
  const int lane = tid & 63, wid = tid >> 6, fr = lane & 15, fq = lane >> 4;
  f32x4 acc0[4] = {}, acc1[4] = {};
  gemm_tiles<2, false>(sdf + (size_t)m0 * 512, 64, Wp1aT + (size_t)n0 * 512,
                       Wp2aT + (size_t)n0 * 512, ldsA, ldsB0, ldsB1, tid, acc0, acc1);
  float dots[4] = {0.f, 0.f, 0.f, 0.f};
#pragma unroll
  for (int r = 0; r < 4; ++r) {
    int row = m0 + wid * 16 + fq * 4 + r;
    int ci = corr_seq[row * Sv + t];
    int qi = q_seq[row * Sv + t + 1];
    int cci = c_seq[row * Sv + t + 1];
    int qdi = qd_seq[row * Sv + t + 1];
    int cdi = cd_seq[row * Sv + t + 1];
#pragma unroll
    for (int ni = 0; ni < 4; ++ni) {
      int col = n0 + ni * 16 + fr;
      float p1 = acc0[ni][r] + bf2f(P1c[ci * 512 + col]);
      float p2 = acc1[ni][r] + bf2f(P2c[ci * 512 + col]);
      float pka = sigm(p1) * tanh_(p2);
      size_t off = (size_t)row * 512 + col;
      float g = gamma[off];
      float h = h_f32[off];
      float hn = g * h + (1.f - g) * pka;
      h_f32[off] = hn;
      h_bf[off] = f2bf(hn);
      float x = XQ[(size_t)qi * 512 + col] + XC[(size_t)cci * 512 + col] +
                XQD[(size_t)qdi * 512 + col] + XCD[(size_t)cdi * 512 + col];
      d_buf[off] = f2bf(x - hn);
      dots[r] += x * hn;
    }
  }
  // reduce over the 16 lanes holding the same row (cols of this block)
#pragma unroll
  for (int r = 0; r < 4; ++r) {
    float v = dots[r];
    v += __shfl_xor(v, 1);
    v += __shfl_xor(v, 2);
    v += __shfl_xor(v, 4);
    v += __shfl_xor(v, 8);
    if (fr == 0) {
      int row = m0 + wid * 16 + fq * 4 + r;
      dotpart[((size_t)t * 8 + nb) * 512 + row] = v;
    }
  }
}

// ---------------- finalize: y = sigmoid(sum of dot partials); last column 0 ----------------
__global__ __launch_bounds__(256) void finalize_k(const float* __restrict__ dotpart,
                                                  float* __restrict__ y) {
  const int i = blockIdx.x * 256 + threadIdx.x;  // 0..102399
  const int b = i / Sv, t = i % Sv;
  float v = 0.f;
  if (t < Sv - 1) {
    float s = 0.f;
#pragma unroll
    for (int nb = 0; nb < 8; ++nb) s += dotpart[((size_t)t * 8 + nb) * 512 + b];
    v = sigm(s);
  }
  y[i] = v;
}

// ---------------- host ----------------
extern "C" void kernel_launch(void* const* d_in, const int* in_sizes, int n_in,
                              void* d_out, int out_size, void* d_ws, size_t ws_size,
                              hipStream_t stream) {
  (void)in_sizes; (void)n_in; (void)out_size; (void)ws_size;
  const int* q_seq    = (const int*)d_in[0];
  const int* c_seq    = (const int*)d_in[1];
  const int* qd_seq   = (const int*)d_in[2];
  const int* cd_seq   = (const int*)d_in[3];
  const int* corr_seq = (const int*)d_in[4];
  const float* E_q    = (const float*)d_in[5];
  const float* E_c    = (const float*)d_in[6];
  const float* E_qd   = (const float*)d_in[7];
  const float* E_cd   = (const float*)d_in[8];
  const float* E_corr = (const float*)d_in[9];
  const float* W_x  = (const float*)d_in[10];
  const float* b_x  = (const float*)d_in[11];
  const float* W_s1 = (const float*)d_in[12];
  const float* b_s1 = (const float*)d_in[13];
  const float* W_s2 = (const float*)d_in[14];
  const float* b_s2 = (const float*)d_in[15];
  const float* W_p1 = (const float*)d_in[16];
  const float* b_p1 = (const float*)d_in[17];
  const float* W_p2 = (const float*)d_in[18];
  const float* b_p2 = (const float*)d_in[19];
  const float* W_ki = (const float*)d_in[20];
  const float* b_ki = (const float*)d_in[21];
  const float* h0   = (const float*)d_in[22];
  float* y = (float*)d_out;

  char* ws = (char*)d_ws;
  size_t off = 0;
  auto alloc = [&](size_t bytes) -> void* {
    void* p = ws + off;
    off += (bytes + 255) & ~(size_t)255;
    return p;
  };
  const size_t WSZ = 512 * 512 * sizeof(u16);
  u16* WxTq  = (u16*)alloc(WSZ);
  u16* WxTc  = (u16*)alloc(WSZ);
  u16* WxTqd = (u16*)alloc(WSZ);
  u16* WxTcd = (u16*)alloc(WSZ);
  u16* Ws1T  = (u16*)alloc(WSZ);
  u16* Ws2T  = (u16*)alloc(WSZ);
  u16* WkihT = (u16*)alloc(WSZ);
  u16* WkiTco = (u16*)alloc(WSZ);
  u16* WkiTqd = (u16*)alloc(WSZ);
  u16* WkiTcd = (u16*)alloc(WSZ);
  u16* Wp1aT = (u16*)alloc(WSZ);
  u16* Wp1hT = (u16*)alloc(WSZ);
  u16* Wp2aT = (u16*)alloc(WSZ);
  u16* Wp2hT = (u16*)alloc(WSZ);
  float* XQf  = (float*)alloc((size_t)10000 * 512 * 4);
  float* XCf  = (float*)alloc((size_t)500 * 512 * 4);
  float* XQDf = (float*)alloc((size_t)101 * 512 * 4);
  float* XCDf = (float*)alloc((size_t)101 * 512 * 4);
  u16* Kcorr = (u16*)alloc((size_t)2 * 512 * 2);
  u16* Kqd   = (u16*)alloc((size_t)101 * 512 * 2);
  u16* Kcd   = (u16*)alloc((size_t)101 * 512 * 2);
  u16* P1c   = (u16*)alloc((size_t)2 * 512 * 2);
  u16* P2c   = (u16*)alloc((size_t)2 * 512 * 2);
  u16* sdf   = (u16*)alloc((size_t)512 * 512 * 2);
  u16* d_buf = (u16*)alloc((size_t)512 * 512 * 2);
  u16* h_bf  = (u16*)alloc((size_t)512 * 512 * 2);
  float* h_f32  = (float*)alloc((size_t)512 * 512 * 4);
  float* gamma  = (float*)alloc((size_t)512 * 512 * 4);
  float* dotpart = (float*)alloc((size_t)199 * 8 * 512 * 4);

  dim3 blk(256);
  dim3 tg(16, 16);
  // weight transpose+bf16 converts (all [512][512] slices)
  convT_k<<<tg, blk, 0, stream>>>(W_x + 0 * 512 * 512, WxTq);
  convT_k<<<tg, blk, 0, stream>>>(W_x + 1 * 512 * 512, WxTc);
  convT_k<<<tg, blk, 0, stream>>>(W_x + 2 * 512 * 512, WxTqd);
  convT_k<<<tg, blk, 0, stream>>>(W_x + 3 * 512 * 512, WxTcd);
  convT_k<<<tg, blk, 0, stream>>>(W_s1, Ws1T);
  convT_k<<<tg, blk, 0, stream>>>(W_s2, Ws2T);
  convT_k<<<tg, blk, 0, stream>>>(W_ki + 0 * 512 * 512, WkihT);
  convT_k<<<tg, blk, 0, stream>>>(W_ki + 1 * 512 * 512, WkiTco);
  convT_k<<<tg, blk, 0, stream>>>(W_ki + 2 * 512 * 512, WkiTqd);
  convT_k<<<tg, blk, 0, stream>>>(W_ki + 3 * 512 * 512, WkiTcd);
  convT_k<<<tg, blk, 0, stream>>>(W_p1 + 0 * 512 * 512, Wp1aT);
  convT_k<<<tg, blk, 0, stream>>>(W_p1 + 1 * 512 * 512, Wp1hT);
  convT_k<<<tg, blk, 0, stream>>>(W_p2 + 0 * 512 * 512, Wp2aT);
  convT_k<<<tg, blk, 0, stream>>>(W_p2 + 1 * 512 * 512, Wp2hT);
  // tables
  gemm_table_k<true><<<dim3(157, 8), blk, 0, stream>>>(E_q, 10000, WxTq, nullptr, XQf);
  gemm_table_k<true><<<dim3(8, 8), blk, 0, stream>>>(E_c, 500, WxTc, b_x, XCf);
  gemm_table_k<true><<<dim3(2, 8), blk, 0, stream>>>(E_qd, 101, WxTqd, nullptr, XQDf);
  gemm_table_k<true><<<dim3(2, 8), blk, 0, stream>>>(E_cd, 101, WxTcd, nullptr, XCDf);
  gemm_table_k<false><<<dim3(1, 8), blk, 0, stream>>>(E_corr, 2, WkiTco, b_ki, Kcorr);
  gemm_table_k<false><<<dim3(2, 8), blk, 0, stream>>>(E_qd, 101, WkiTqd, nullptr, Kqd);
  gemm_table_k<false><<<dim3(2, 8), blk, 0, stream>>>(E_cd, 101, WkiTcd, nullptr, Kcd);
  gemm_table_k<false><<<dim3(1, 8), blk, 0, stream>>>(E_corr, 2, Wp1hT, b_p1, P1c);
  gemm_table_k<false><<<dim3(1, 8), blk, 0, stream>>>(E_corr, 2, Wp2hT, b_p2, P2c);
  // prologue
  prologue_k<<<dim3(1024), blk, 0, stream>>>(h0, q_seq, c_seq, qd_seq, cd_seq,
                                             XQf, XCf, XQDf, XCDf, h_f32, h_bf, d_buf);
  // sequential scan
  for (int t = 0; t < Sv - 1; ++t) {
    k1_kernel<<<dim3(128), blk, 0, stream>>>(d_buf, h_bf, Ws1T, Ws2T, WkihT, b_s1, b_s2,
                                             Kcorr, Kqd, Kcd, corr_seq, qd_seq, cd_seq,
                                             sdf, gamma, t);
    k2_kernel<<<dim3(64), blk, 0, stream>>>(sdf, Wp1aT, Wp2aT, P1c, P2c, corr_seq, q_seq,
                                            c_seq, qd_seq, cd_seq, XQf, XCf, XQDf, XCDf,
                                            gamma, h_f32, h_bf, d_buf, dotpart, t);
  }
  // finalize
  finalize_k<<<dim3(400), blk, 0, stream>>>(dotpart, y);
}

// Round 2
// 4797.670 us; speedup vs baseline: 1.1068x; 1.1068x over previous
//
#include <hip/hip_runtime.h>

// DIMKT round 1: persistent cooperative scan kernel.
//   - precompute (round-0 machinery): 14 weight transposes, 9 table GEMMs,
//     seq transpose, prologue (h_bf0, d0, zero flags/dotacc)
//   - scan_k: 256 WGs = 8 m-groups (64 rows) x 32 n-slices (16 cols).
//     Weights LDS-resident (80KB/WG, XOR-swizzled chunks). Per step:
//     phase1 sdf tile -> m-group barrier -> phase2 gamma/pka/h-update/d/x/dots
//     -> m-group barrier. h carried in f32 registers.
//   - finalize: y = sigmoid(dotacc), last col 0.

typedef unsigned short u16;
using f32x4 = __attribute__((ext_vector_type(4))) float;
using bf16x8 = __attribute__((ext_vector_type(8))) short;

#define DEV static __device__ __forceinline__

#define Bv 512
#define Sv 200
#define Dv 512

DEV u16 f2bf(float f) {
  unsigned int u = __float_as_uint(f);
  unsigned int r = (u + 0x7fffu + ((u >> 16) & 1u)) >> 16;
  return (u16)r;
}
DEV float bf2f(u16 h) { return __uint_as_float(((unsigned int)h) << 16); }
DEV float sigm(float x) { return 1.0f / (1.0f + __expf(-x)); }
DEV float tanh_(float x) {
  x = fmaxf(fminf(x, 15.f), -15.f);
  float e = __expf(2.0f * x);
  return (e - 1.0f) / (e + 1.0f);
}
DEV f32x4 MF(bf16x8 a, bf16x8 b, f32x4 c) {
  return __builtin_amdgcn_mfma_f32_16x16x32_bf16(a, b, c, 0, 0, 0);
}

// ================= precompute machinery (round-0, verified) =================
template <int NB, bool AF32>
DEV void gemm_tiles(const void* __restrict__ Aptr, int mvalid,
                    const u16* __restrict__ BT0, const u16* __restrict__ BT1,
                    u16* ldsA, u16* ldsB0, u16* ldsB1, int tid,
                    f32x4* acc0, f32x4* acc1) {
  const int lane = tid & 63, wid = tid >> 6;
  const int fr = lane & 15, fq = lane >> 4;
  const int srow = tid >> 2, sseg = tid & 3;

  for (int kt = 0; kt < 16; ++kt) {
    const int k0 = kt * 32;
    {
      bf16x8 pack;
      if constexpr (AF32) {
        if (srow < mvalid) {
          const float4* ap = (const float4*)((const float*)Aptr + (size_t)srow * 512 + k0 + sseg * 8);
          float4 v0 = ap[0], v1 = ap[1];
          pack[0] = (short)f2bf(v0.x); pack[1] = (short)f2bf(v0.y);
          pack[2] = (short)f2bf(v0.z); pack[3] = (short)f2bf(v0.w);
          pack[4] = (short)f2bf(v1.x); pack[5] = (short)f2bf(v1.y);
          pack[6] = (short)f2bf(v1.z); pack[7] = (short)f2bf(v1.w);
        } else {
          for (int j = 0; j < 8; ++j) pack[j] = 0;
        }
      } else {
        pack = *(const bf16x8*)((const u16*)Aptr + (size_t)srow * 512 + k0 + sseg * 8);
      }
      *(bf16x8*)&ldsA[srow * 40 + sseg * 8] = pack;
      *(bf16x8*)&ldsB0[srow * 40 + sseg * 8] =
          *(const bf16x8*)(BT0 + (size_t)srow * 512 + k0 + sseg * 8);
      if constexpr (NB == 2)
        *(bf16x8*)&ldsB1[srow * 40 + sseg * 8] =
            *(const bf16x8*)(BT1 + (size_t)srow * 512 + k0 + sseg * 8);
    }
    __syncthreads();
    bf16x8 a = *(const bf16x8*)&ldsA[(wid * 16 + fr) * 40 + fq * 8];
#pragma unroll
    for (int ni = 0; ni < 4; ++ni) {
      bf16x8 b0 = *(const bf16x8*)&ldsB0[(ni * 16 + fr) * 40 + fq * 8];
      acc0[ni] = MF(a, b0, acc0[ni]);
      if constexpr (NB == 2) {
        bf16x8 b1 = *(const bf16x8*)&ldsB1[(ni * 16 + fr) * 40 + fq * 8];
        acc1[ni] = MF(a, b1, acc1[ni]);
      }
    }
    __syncthreads();
  }
}

template <bool F32OUT>
__global__ __launch_bounds__(256) void gemm_table_k(const float* __restrict__ A, int M,
                                                    const u16* __restrict__ BT,
                                                    const float* __restrict__ bias,
                                                    void* __restrict__ C) {
  __shared__ u16 ldsA[64 * 40], ldsB[64 * 40];
  const int m0 = blockIdx.x * 64, n0 = blockIdx.y * 64;
  const int tid = threadIdx.x;
  f32x4 acc[4] = {};
  gemm_tiles<1, true>(A + (size_t)m0 * 512, M - m0, BT + (size_t)n0 * 512, nullptr,
                      ldsA, ldsB, nullptr, tid, acc, nullptr);
  const int lane = tid & 63, wid = tid >> 6, fr = lane & 15, fq = lane >> 4;
#pragma unroll
  for (int ni = 0; ni < 4; ++ni) {
    int col = n0 + ni * 16 + fr;
    float bv = bias ? bias[col] : 0.f;
#pragma unroll
    for (int r = 0; r < 4; ++r) {
      int row = m0 + wid * 16 + fq * 4 + r;
      if (row < M) {
        float v = acc[ni][r] + bv;
        if constexpr (F32OUT)
          ((float*)C)[(size_t)row * 512 + col] = v;
        else
          ((u16*)C)[(size_t)row * 512 + col] = f2bf(v);
      }
    }
  }
}

__global__ __launch_bounds__(256) void convT_k(const float* __restrict__ src, u16* __restrict__ dst) {
  __shared__ float tile[32][33];
  const int bi = blockIdx.x, bj = blockIdx.y;
  const int tx = threadIdx.x & 31, ty = threadIdx.x >> 5;
#pragma unroll
  for (int r = 0; r < 4; ++r)
    tile[ty + 8 * r][tx] = src[(size_t)(bj * 32 + ty + 8 * r) * 512 + bi * 32 + tx];
  __syncthreads();
#pragma unroll
  for (int r = 0; r < 4; ++r)
    dst[(size_t)(bi * 32 + ty + 8 * r) * 512 + bj * 32 + tx] = f2bf(tile[tx][ty + 8 * r]);
}

// seq transpose: in[b*200+t] -> out[t*512+b]
__global__ __launch_bounds__(256) void seqT_k(
    const int* __restrict__ q, const int* __restrict__ c, const int* __restrict__ qd,
    const int* __restrict__ cd, const int* __restrict__ corr,
    int* __restrict__ qT, int* __restrict__ cT, int* __restrict__ qdT,
    int* __restrict__ cdT, int* __restrict__ corrT) {
  const int i = blockIdx.x * 256 + threadIdx.x;  // 0 .. 102399
  const int b = i / Sv, t = i % Sv;
  const int o = t * Bv + b;
  qT[o] = q[i]; cT[o] = c[i]; qdT[o] = qd[i]; cdT[o] = cd[i]; corrT[o] = corr[i];
}

// prologue: h_bf0 = bf16(h0), d0 = bf16(x0 - h0); zero flags + dotacc
__global__ __launch_bounds__(256) void prologue_k(
    const float* __restrict__ h0, const int* __restrict__ qT, const int* __restrict__ cT,
    const int* __restrict__ qdT, const int* __restrict__ cdT,
    const float* __restrict__ XQ, const float* __restrict__ XC, const float* __restrict__ XQD,
    const float* __restrict__ XCD, u16* __restrict__ hb0, u16* __restrict__ d_buf,
    float* __restrict__ dotacc, unsigned* __restrict__ flags) {
  const int i = blockIdx.x * 256 + threadIdx.x;  // 0 .. 512*512-1
  if (i < 128) flags[i] = 0u;
  if (i < 199 * Bv) dotacc[i] = 0.f;
  const int b = i >> 9, col = i & 511;
  float h = h0[i];
  int qi = qT[b], cci = cT[b], qdi = qdT[b], cdi = cdT[b];  // t=0 slice
  float x = XQ[(size_t)qi * 512 + col] + XC[(size_t)cci * 512 + col] +
            XQD[(size_t)qdi * 512 + col] + XCD[(size_t)cdi * 512 + col];
  hb0[i] = f2bf(h);
  d_buf[i] = f2bf(x - h);
}

// ================= persistent scan kernel =================
// LDS weight chunk layout: per matrix 16KB = [kc 0..15][64 slots][8 bf16]
// slot(c,q) = c*4 + (q ^ (c&3) ^ ((c>>2)&3))  (bijective; <=2-way bank alias)
DEV void load_wslice(const u16* __restrict__ src, u16* dst, int n0, int tid) {
  for (int i = tid; i < 1024; i += 256) {  // 16B pieces
    int q = i & 3, kc = (i >> 2) & 15, c = i >> 6;
    int slot = c * 4 + (q ^ (c & 3) ^ ((c >> 2) & 3));
    *(bf16x8*)&dst[kc * 512 + slot * 8] =
        *(const bf16x8*)&src[(size_t)(n0 + c) * 512 + kc * 32 + q * 8];
  }
}

DEV void mg_arrive(unsigned* flag) {
  __syncthreads();  // all waves' stores drained (vmcnt 0) before barrier exit
  if (threadIdx.x == 0)
    __hip_atomic_fetch_add(flag, 1u, __ATOMIC_RELEASE, __HIP_MEMORY_SCOPE_AGENT);
}
DEV void mg_wait(unsigned* flag, unsigned target) {
  if (threadIdx.x == 0) {
    while (__hip_atomic_load(flag, __ATOMIC_RELAXED, __HIP_MEMORY_SCOPE_AGENT) < target)
      __builtin_amdgcn_s_sleep(2);
    (void)__hip_atomic_load(flag, __ATOMIC_ACQUIRE, __HIP_MEMORY_SCOPE_AGENT);
  }
  __syncthreads();
}

__global__ __launch_bounds__(256) void scan_k(
    const u16* __restrict__ Ws1T, const u16* __restrict__ Ws2T, const u16* __restrict__ WkihT,
    const u16* __restrict__ Wp1aT, const u16* __restrict__ Wp2aT,
    const float* __restrict__ b_s1, const float* __restrict__ b_s2,
    const u16* __restrict__ Kcorr, const u16* __restrict__ Kqd, const u16* __restrict__ Kcd,
    const u16* __restrict__ P1c, const u16* __restrict__ P2c,
    const int* __restrict__ qT, const int* __restrict__ cT, const int* __restrict__ qdT,
    const int* __restrict__ cdT, const int* __restrict__ corrT,
    const float* __restrict__ XQ, const float* __restrict__ XC, const float* __restrict__ XQD,
    const float* __restrict__ XCD, const float* __restrict__ h0,
    u16* __restrict__ sdf, u16* __restrict__ dbuf, u16* __restrict__ hb0, u16* __restrict__ hb1,
    float* __restrict__ dotacc, unsigned* __restrict__ flags) {
  __shared__ u16 wlds[40960];  // 5 x 16KB
  const int bid = blockIdx.x;
  const int mg = bid & 7, ng = bid >> 3;  // bid%8 -> XCD pin under round-robin dispatch
  const int m0 = mg * 64, n0 = ng * 16;
  const int tid = threadIdx.x, lane = tid & 63, w = tid >> 6;
  const int fr = lane & 15, fq = lane >> 4;

  load_wslice(Ws1T,  wlds + 0 * 8192, n0, tid);
  load_wslice(Ws2T,  wlds + 1 * 8192, n0, tid);
  load_wslice(WkihT, wlds + 2 * 8192, n0, tid);
  load_wslice(Wp1aT, wlds + 3 * 8192, n0, tid);
  load_wslice(Wp2aT, wlds + 4 * 8192, n0, tid);

  const int col = n0 + fr;
  const float bs1 = b_s1[col], bs2 = b_s2[col];
  const float kco0 = bf2f(Kcorr[col]),      kco1 = bf2f(Kcorr[512 + col]);
  const float p1c0 = bf2f(P1c[col]),        p1c1 = bf2f(P1c[512 + col]);
  const float p2c0 = bf2f(P2c[col]),        p2c1 = bf2f(P2c[512 + col]);

  const int crow0 = m0 + w * 16 + fq * 4;  // C-layout rows (r = 0..3)
  float hl[4];
#pragma unroll
  for (int r = 0; r < 4; ++r) hl[r] = h0[(size_t)(crow0 + r) * 512 + col];

  const int slot = fr * 4 + (fq ^ (fr & 3) ^ ((fr >> 2) & 3));
  const u16* wb = wlds + slot * 8;
  const size_t aoff = (size_t)(m0 + w * 16 + fr) * 512 + fq * 8;  // A-frag base (elems)

  unsigned* flag = flags + mg * 16;  // 64B spacing
  __syncthreads();

  for (int t = 0; t < Sv - 1; ++t) {
    // ---------- phase 1: sdf tile ----------
    f32x4 a1 = {}, a2 = {};
#pragma unroll
    for (int kc = 0; kc < 16; ++kc) {
      bf16x8 av = *(const bf16x8*)(dbuf + aoff + kc * 32);
      bf16x8 b1 = *(const bf16x8*)(wb + 0 * 8192 + kc * 512);
      bf16x8 b2 = *(const bf16x8*)(wb + 1 * 8192 + kc * 512);
      a1 = MF(av, b1, a1);
      a2 = MF(av, b2, a2);
    }
#pragma unroll
    for (int r = 0; r < 4; ++r)
      sdf[(size_t)(crow0 + r) * 512 + col] = f2bf(sigm(a1[r] + bs1) * tanh_(a2[r] + bs2));
    mg_arrive(flag);
    mg_wait(flag, 32u * (unsigned)(2 * t + 1));

    // ---------- phase 2: gamma, pka, h/d update, dots ----------
    const u16* hb = (t & 1) ? hb1 : hb0;
    u16* hbn      = (t & 1) ? hb0 : hb1;
    f32x4 ag = {}, ap1 = {}, ap2 = {};
#pragma unroll
    for (int kc = 0; kc < 16; ++kc) {
      bf16x8 as = *(const bf16x8*)(sdf + aoff + kc * 32);
      bf16x8 ah = *(const bf16x8*)(hb + aoff + kc * 32);
      bf16x8 bk = *(const bf16x8*)(wb + 2 * 8192 + kc * 512);
      bf16x8 bp1 = *(const bf16x8*)(wb + 3 * 8192 + kc * 512);
      bf16x8 bp2 = *(const bf16x8*)(wb + 4 * 8192 + kc * 512);
      ag  = MF(ah, bk, ag);
      ap1 = MF(as, bp1, ap1);
      ap2 = MF(as, bp2, ap2);
    }
    float dots[4];
#pragma unroll
    for (int r = 0; r < 4; ++r) {
      const int row = crow0 + r;
      int ci  = corrT[t * Bv + row];
      int qdi = qdT[t * Bv + row];
      int cdi = cdT[t * Bv + row];
      float g = sigm(ag[r] + (ci ? kco1 : kco0) + bf2f(Kqd[qdi * 512 + col]) +
                     bf2f(Kcd[cdi * 512 + col]));
      float pka = sigm(ap1[r] + (ci ? p1c1 : p1c0)) * tanh_(ap2[r] + (ci ? p2c1 : p2c0));
      float hn = g * hl[r] + (1.f - g) * pka;
      hl[r] = hn;
      int qi   = qT[(t + 1) * Bv + row];
      int cci  = cT[(t + 1) * Bv + row];
      int qdi2 = qdT[(t + 1) * Bv + row];
      int cdi2 = cdT[(t + 1) * Bv + row];
      float x = XQ[(size_t)qi * 512 + col] + XC[(size_t)cci * 512 + col] +
                XQD[(size_t)qdi2 * 512 + col] + XCD[(size_t)cdi2 * 512 + col];
      hbn[(size_t)row * 512 + col] = f2bf(hn);
      dbuf[(size_t)row * 512 + col] = f2bf(x - hn);
      dots[r] = x * hn;
    }
#pragma unroll
    for (int r = 0; r < 4; ++r) {
      float v = dots[r];
      v += __shfl_xor(v, 1);
      v += __shfl_xor(v, 2);
      v += __shfl_xor(v, 4);
      v += __shfl_xor(v, 8);
      if (fr == 0) atomicAdd(&dotacc[t * Bv + crow0 + r], v);
    }
    mg_arrive(flag);
    mg_wait(flag, 32u * (unsigned)(2 * t + 2));
  }
}

// ================= finalize =================
__global__ __launch_bounds__(256) void finalize_k(const float* __restrict__ dotacc,
                                                  float* __restrict__ y) {
  const int i = blockIdx.x * 256 + threadIdx.x;  // 0..102399
  const int b = i / Sv, t = i % Sv;
  y[i] = (t < Sv - 1) ? sigm(dotacc[t * Bv + b]) : 0.f;
}

// ================= host =================
extern "C" void kernel_launch(void* const* d_in, const int* in_sizes, int n_in,
                              void* d_out, int out_size, void* d_ws, size_t ws_size,
                              hipStream_t stream) {
  (void)in_sizes; (void)n_in; (void)out_size; (void)ws_size;
  const int* q_seq    = (const int*)d_in[0];
  const int* c_seq    = (const int*)d_in[1];
  const int* qd_seq   = (const int*)d_in[2];
  const int* cd_seq   = (const int*)d_in[3];
  const int* corr_seq = (const int*)d_in[4];
  const float* E_q    = (const float*)d_in[5];
  const float* E_c    = (const float*)d_in[6];
  const float* E_qd   = (const float*)d_in[7];
  const float* E_cd   = (const float*)d_in[8];
  const float* E_corr = (const float*)d_in[9];
  const float* W_x  = (const float*)d_in[10];
  const float* b_x  = (const float*)d_in[11];
  const float* W_s1 = (const float*)d_in[12];
  const float* b_s1 = (const float*)d_in[13];
  const float* W_s2 = (const float*)d_in[14];
  const float* b_s2 = (const float*)d_in[15];
  const float* W_p1 = (const float*)d_in[16];
  const float* b_p1 = (const float*)d_in[17];
  const float* W_p2 = (const float*)d_in[18];
  const float* b_p2 = (const float*)d_in[19];
  const float* W_ki = (const float*)d_in[20];
  const float* b_ki = (const float*)d_in[21];
  const float* h0   = (const float*)d_in[22];
  float* y = (float*)d_out;

  char* ws = (char*)d_ws;
  size_t off = 0;
  auto alloc = [&](size_t bytes) -> void* {
    void* p = ws + off;
    off += (bytes + 255) & ~(size_t)255;
    return p;
  };
  const size_t WSZ = 512 * 512 * sizeof(u16);
  u16* WxTq  = (u16*)alloc(WSZ);
  u16* WxTc  = (u16*)alloc(WSZ);
  u16* WxTqd = (u16*)alloc(WSZ);
  u16* WxTcd = (u16*)alloc(WSZ);
  u16* Ws1T  = (u16*)alloc(WSZ);
  u16* Ws2T  = (u16*)alloc(WSZ);
  u16* WkihT = (u16*)alloc(WSZ);
  u16* WkiTco = (u16*)alloc(WSZ);
  u16* WkiTqd = (u16*)alloc(WSZ);
  u16* WkiTcd = (u16*)alloc(WSZ);
  u16* Wp1aT = (u16*)alloc(WSZ);
  u16* Wp1hT = (u16*)alloc(WSZ);
  u16* Wp2aT = (u16*)alloc(WSZ);
  u16* Wp2hT = (u16*)alloc(WSZ);
  float* XQf  = (float*)alloc((size_t)10000 * 512 * 4);
  float* XCf  = (float*)alloc((size_t)500 * 512 * 4);
  float* XQDf = (float*)alloc((size_t)101 * 512 * 4);
  float* XCDf = (float*)alloc((size_t)101 * 512 * 4);
  u16* Kcorr = (u16*)alloc((size_t)2 * 512 * 2);
  u16* Kqd   = (u16*)alloc((size_t)101 * 512 * 2);
  u16* Kcd   = (u16*)alloc((size_t)101 * 512 * 2);
  u16* P1c   = (u16*)alloc((size_t)2 * 512 * 2);
  u16* P2c   = (u16*)alloc((size_t)2 * 512 * 2);
  u16* sdf   = (u16*)alloc((size_t)512 * 512 * 2);
  u16* d_buf = (u16*)alloc((size_t)512 * 512 * 2);
  u16* hb0   = (u16*)alloc((size_t)512 * 512 * 2);
  u16* hb1   = (u16*)alloc((size_t)512 * 512 * 2);
  float* dotacc = (float*)alloc((size_t)199 * 512 * 4);
  int* qT    = (int*)alloc((size_t)Sv * Bv * 4);
  int* cT    = (int*)alloc((size_t)Sv * Bv * 4);
  int* qdT   = (int*)alloc((size_t)Sv * Bv * 4);
  int* cdT   = (int*)alloc((size_t)Sv * Bv * 4);
  int* corrT = (int*)alloc((size_t)Sv * Bv * 4);
  unsigned* flags = (unsigned*)alloc(128 * 4);

  dim3 blk(256);
  dim3 tg(16, 16);
  convT_k<<<tg, blk, 0, stream>>>(W_x + 0 * 512 * 512, WxTq);
  convT_k<<<tg, blk, 0, stream>>>(W_x + 1 * 512 * 512, WxTc);
  convT_k<<<tg, blk, 0, stream>>>(W_x + 2 * 512 * 512, WxTqd);
  convT_k<<<tg, blk, 0, stream>>>(W_x + 3 * 512 * 512, WxTcd);
  convT_k<<<tg, blk, 0, stream>>>(W_s1, Ws1T);
  convT_k<<<tg, blk, 0, stream>>>(W_s2, Ws2T);
  convT_k<<<tg, blk, 0, stream>>>(W_ki + 0 * 512 * 512, WkihT);
  convT_k<<<tg, blk, 0, stream>>>(W_ki + 1 * 512 * 512, WkiTco);
  convT_k<<<tg, blk, 0, stream>>>(W_ki + 2 * 512 * 512, WkiTqd);
  convT_k<<<tg, blk, 0, stream>>>(W_ki + 3 * 512 * 512, WkiTcd);
  convT_k<<<tg, blk, 0, stream>>>(W_p1 + 0 * 512 * 512, Wp1aT);
  convT_k<<<tg, blk, 0, stream>>>(W_p1 + 1 * 512 * 512, Wp1hT);
  convT_k<<<tg, blk, 0, stream>>>(W_p2 + 0 * 512 * 512, Wp2aT);
  convT_k<<<tg, blk, 0, stream>>>(W_p2 + 1 * 512 * 512, Wp2hT);

  gemm_table_k<true><<<dim3(157, 8), blk, 0, stream>>>(E_q, 10000, WxTq, nullptr, XQf);
  gemm_table_k<true><<<dim3(8, 8), blk, 0, stream>>>(E_c, 500, WxTc, b_x, XCf);
  gemm_table_k<true><<<dim3(2, 8), blk, 0, stream>>>(E_qd, 101, WxTqd, nullptr, XQDf);
  gemm_table_k<true><<<dim3(2, 8), blk, 0, stream>>>(E_cd, 101, WxTcd, nullptr, XCDf);
  gemm_table_k<false><<<dim3(1, 8), blk, 0, stream>>>(E_corr, 2, WkiTco, b_ki, Kcorr);
  gemm_table_k<false><<<dim3(2, 8), blk, 0, stream>>>(E_qd, 101, WkiTqd, nullptr, Kqd);
  gemm_table_k<false><<<dim3(2, 8), blk, 0, stream>>>(E_cd, 101, WkiTcd, nullptr, Kcd);
  gemm_table_k<false><<<dim3(1, 8), blk, 0, stream>>>(E_corr, 2, Wp1hT, b_p1, P1c);
  gemm_table_k<false><<<dim3(1, 8), blk, 0, stream>>>(E_corr, 2, Wp2hT, b_p2, P2c);

  seqT_k<<<dim3(400), blk, 0, stream>>>(q_seq, c_seq, qd_seq, cd_seq, corr_seq,
                                        qT, cT, qdT, cdT, corrT);
  prologue_k<<<dim3(1024), blk, 0, stream>>>(h0, qT, cT, qdT, cdT, XQf, XCf, XQDf, XCDf,
                                             hb0, d_buf, dotacc, flags);

  // persistent scan (cooperative for guaranteed co-residency)
  {
    const u16 *a0 = Ws1T, *a1 = Ws2T, *a2 = WkihT, *a3 = Wp1aT, *a4 = Wp2aT;
    const float *a5 = b_s1, *a6 = b_s2;
    const u16 *a7 = Kcorr, *a8 = Kqd, *a9 = Kcd, *a10 = P1c, *a11 = P2c;
    const int *a12 = qT, *a13 = cT, *a14 = qdT, *a15 = cdT, *a16 = corrT;
    const float *a17 = XQf, *a18 = XCf, *a19 = XQDf, *a20 = XCDf, *a21 = h0;
    u16 *a22 = sdf, *a23 = d_buf, *a24 = hb0, *a25 = hb1;
    float* a26 = dotacc;
    unsigned* a27 = flags;
    void* args[] = {&a0, &a1, &a2, &a3, &a4, &a5, &a6, &a7, &a8, &a9, &a10, &a11,
                    &a12, &a13, &a14, &a15, &a16, &a17, &a18, &a19, &a20, &a21,
                    &a22, &a23, &a24, &a25, &a26, &a27};
    hipError_t e = hipLaunchCooperativeKernel((void*)scan_k, dim3(256), dim3(256),
                                              args, 0, stream);
    if (e != hipSuccess) {
      // fallback: plain launch (256 blocks <= 256 CUs, 80KB LDS -> co-resident)
      scan_k<<<dim3(256), blk, 0, stream>>>(Ws1T, Ws2T, WkihT, Wp1aT, Wp2aT, b_s1, b_s2,
                                            Kcorr, Kqd, Kcd, P1c, P2c, qT, cT, qdT, cdT,
                                            corrT, XQf, XCf, XQDf, XCDf, h0, sdf, d_buf,
                                            hb0, hb1, dotacc, flags);
    }
  }

  finalize_k<<<dim3(400), blk, 0, stream>>>(dotacc, y);
}